// Round 2
// baseline (299.872 us; speedup 1.0000x reference)
//
#include <hip/hip_runtime.h>

#define INPUT_SIZE 128
#define OUTPUT_SIZE 128
#define HIDDEN 8
#define BATCH 1024
#define NSUB (INPUT_SIZE * OUTPUT_SIZE)

// ---------------------------------------------------------------------------
// Transpose x [B=1024, I=128] -> xT [I=128, B=1024] so the main kernel's
// per-i batch reads are lane-coalesced. 32x32 LDS tiles, +1 pad.
// grid: (I/32=4, B/32=32), block: (32, 8)
// ---------------------------------------------------------------------------
__global__ void transpose_x_kernel(const float* __restrict__ x,
                                   float* __restrict__ xT) {
    __shared__ float tile[32][33];
    const int i0 = blockIdx.x * 32;
    const int b0 = blockIdx.y * 32;
    const int tx = threadIdx.x;   // 0..31
    const int ty = threadIdx.y;   // 0..7
#pragma unroll
    for (int r = ty; r < 32; r += 8) {
        tile[r][tx] = x[(b0 + r) * INPUT_SIZE + (i0 + tx)];
    }
    __syncthreads();
#pragma unroll
    for (int r = ty; r < 32; r += 8) {
        xT[(i0 + r) * BATCH + (b0 + tx)] = tile[tx][r];
    }
}

// ---------------------------------------------------------------------------
// Main kernel. One block per (o, batch-tile of 256). Thread t = batch
// b = btile*256 + t. Loop over i: n = i*128 + o has a block-uniform address,
// so all 97 weights should compile to scalar (s_load) traffic; the inner
// loops are pure fp32 FMA chains with SGPR weight operands.
// XT=true: read from transposed xT[i*BATCH+b] (coalesced).
// XT=false: read x[b*INPUT+i] directly (fallback if ws too small).
// ---------------------------------------------------------------------------
template <bool XT>
__global__ __launch_bounds__(256, 2)
void mlpkan_kernel(const float* __restrict__ xsrc,
                   const float* __restrict__ W1, const float* __restrict__ b1,
                   const float* __restrict__ W2, const float* __restrict__ b2,
                   const float* __restrict__ W3, const float* __restrict__ b3,
                   float* __restrict__ out) {
    const int o = blockIdx.x;                       // 0..127
    const int b = blockIdx.y * 256 + threadIdx.x;   // 0..1023

    float acc = 0.0f;

    for (int i = 0; i < INPUT_SIZE; ++i) {
        const int n = i * OUTPUT_SIZE + o;          // block-uniform

        const float s = XT ? xsrc[i * BATCH + b] : xsrc[b * INPUT_SIZE + i];

        const float* __restrict__ w1  = W1 + (size_t)n * HIDDEN;  // [h][1]
        const float* __restrict__ bb1 = b1 + (size_t)n * HIDDEN;
        const float* __restrict__ w2  = W2 + (size_t)n * HIDDEN * HIDDEN;
        const float* __restrict__ bb2 = b2 + (size_t)n * HIDDEN;
        const float* __restrict__ w3  = W3 + (size_t)n * HIDDEN;  // [1][h]

        // layer 1: h1 = relu(W1 * s + b1)
        float h1[HIDDEN];
#pragma unroll
        for (int k = 0; k < HIDDEN; ++k) {
            float v = fmaf(w1[k], s, bb1[k]);
            h1[k] = v > 0.0f ? v : 0.0f;
        }

        // layer 2: h2 = relu(W2 @ h1 + b2)   (W2 row-major [h][k])
        float h2[HIDDEN];
#pragma unroll
        for (int h = 0; h < HIDDEN; ++h) {
            float v = bb2[h];
#pragma unroll
            for (int k = 0; k < HIDDEN; ++k) {
                v = fmaf(w2[h * HIDDEN + k], h1[k], v);
            }
            h2[h] = v > 0.0f ? v : 0.0f;
        }

        // layer 3: scalar = W3 . h2 + b3
        float v = b3[n];
#pragma unroll
        for (int k = 0; k < HIDDEN; ++k) {
            v = fmaf(w3[k], h2[k], v);
        }
        acc += v;
    }

    out[(size_t)b * OUTPUT_SIZE + o] = acc;
}

extern "C" void kernel_launch(void* const* d_in, const int* in_sizes, int n_in,
                              void* d_out, int out_size, void* d_ws, size_t ws_size,
                              hipStream_t stream) {
    const float* x  = (const float*)d_in[0];
    const float* W1 = (const float*)d_in[1];
    const float* b1 = (const float*)d_in[2];
    const float* W2 = (const float*)d_in[3];
    const float* b2 = (const float*)d_in[4];
    const float* W3 = (const float*)d_in[5];
    const float* b3 = (const float*)d_in[6];
    float* out = (float*)d_out;

    const size_t xt_bytes = (size_t)INPUT_SIZE * BATCH * sizeof(float);

    if (ws_size >= xt_bytes) {
        float* xT = (float*)d_ws;
        dim3 tgrid(INPUT_SIZE / 32, BATCH / 32);
        dim3 tblk(32, 8);
        transpose_x_kernel<<<tgrid, tblk, 0, stream>>>(x, xT);

        dim3 grid(OUTPUT_SIZE, BATCH / 256);
        mlpkan_kernel<true><<<grid, 256, 0, stream>>>(xT, W1, b1, W2, b2, W3, b3, out);
    } else {
        dim3 grid(OUTPUT_SIZE, BATCH / 256);
        mlpkan_kernel<false><<<grid, 256, 0, stream>>>(x, W1, b1, W2, b2, W3, b3, out);
    }
}

// Round 3
// 160.351 us; speedup vs baseline: 1.8701x; 1.8701x over previous
//
#include <hip/hip_runtime.h>

#define INPUT_SIZE 128
#define OUTPUT_SIZE 128
#define HIDDEN 8
#define BATCH 1024

#define BPT 4           // batch elements per thread
#define ICH 8           // i-chunks (blockIdx.y)
#define IPC (INPUT_SIZE / ICH)   // 16 i's per chunk

// ---------------------------------------------------------------------------
// Transpose x [B=1024, I=128] -> xT [I=128, B=1024] (coalesced main reads).
// grid: (4, 32), block: (32, 8)
// ---------------------------------------------------------------------------
__global__ void transpose_x_kernel(const float* __restrict__ x,
                                   float* __restrict__ xT) {
    __shared__ float tile[32][33];
    const int i0 = blockIdx.x * 32;
    const int b0 = blockIdx.y * 32;
    const int tx = threadIdx.x;
    const int ty = threadIdx.y;
#pragma unroll
    for (int r = ty; r < 32; r += 8)
        tile[r][tx] = x[(b0 + r) * INPUT_SIZE + (i0 + tx)];
    __syncthreads();
#pragma unroll
    for (int r = ty; r < 32; r += 8)
        xT[(i0 + r) * BATCH + (b0 + tx)] = tile[tx][r];
}

__global__ void zero_out_kernel(float* __restrict__ out, int n) {
    int idx = blockIdx.x * blockDim.x + threadIdx.x;
    if (idx < n) out[idx] = 0.0f;
}

// ---------------------------------------------------------------------------
// Main kernel. blockIdx.x = o (0..127), blockIdx.y = i-chunk (0..ICH-1).
// Thread t handles batches b = t, t+256, t+512, t+768 (BPT=4 ILP chains).
// n = i*128+o is block-uniform -> weights via scalar loads, reused across
// the 4 batch chains. PARTIALS: write per-chunk partial sums to ws
// (layout [ic][o][b], coalesced); else atomicAdd into out.
// ---------------------------------------------------------------------------
template <bool PARTIALS>
__global__ __launch_bounds__(256, 4)
void mlpkan_kernel(const float* __restrict__ xT,
                   const float* __restrict__ W1, const float* __restrict__ b1,
                   const float* __restrict__ W2, const float* __restrict__ b2,
                   const float* __restrict__ W3, const float* __restrict__ b3,
                   float* __restrict__ partials, float* __restrict__ out) {
    const int o   = blockIdx.x;
    const int ic  = blockIdx.y;
    const int tid = threadIdx.x;

    float acc[BPT];
#pragma unroll
    for (int j = 0; j < BPT; ++j) acc[j] = 0.0f;

    for (int ii = 0; ii < IPC; ++ii) {
        const int i = ic * IPC + ii;
        const int n = i * OUTPUT_SIZE + o;          // block-uniform

        const float* __restrict__ w1  = W1 + (size_t)n * HIDDEN;
        const float* __restrict__ bb1 = b1 + (size_t)n * HIDDEN;
        const float* __restrict__ w2  = W2 + (size_t)n * HIDDEN * HIDDEN;
        const float* __restrict__ bb2 = b2 + (size_t)n * HIDDEN;
        const float* __restrict__ w3  = W3 + (size_t)n * HIDDEN;
        const float  bb3 = b3[n];

        float s[BPT];
#pragma unroll
        for (int j = 0; j < BPT; ++j)
            s[j] = xT[(size_t)i * BATCH + tid + j * 256];

#pragma unroll
        for (int j = 0; j < BPT; ++j) {
            float h1[HIDDEN];
#pragma unroll
            for (int k = 0; k < HIDDEN; ++k) {
                float v = fmaf(w1[k], s[j], bb1[k]);
                h1[k] = v > 0.0f ? v : 0.0f;
            }
            float h2[HIDDEN];
#pragma unroll
            for (int h = 0; h < HIDDEN; ++h) {
                float v = bb2[h];
#pragma unroll
                for (int k = 0; k < HIDDEN; ++k)
                    v = fmaf(w2[h * HIDDEN + k], h1[k], v);
                h2[h] = v > 0.0f ? v : 0.0f;
            }
            float v = bb3;
#pragma unroll
            for (int k = 0; k < HIDDEN; ++k)
                v = fmaf(w3[k], h2[k], v);
            acc[j] += v;
        }
    }

    if (PARTIALS) {
#pragma unroll
        for (int j = 0; j < BPT; ++j)
            partials[((size_t)ic * OUTPUT_SIZE + o) * BATCH + tid + j * 256] = acc[j];
    } else {
#pragma unroll
        for (int j = 0; j < BPT; ++j)
            atomicAdd(&out[(size_t)(tid + j * 256) * OUTPUT_SIZE + o], acc[j]);
    }
}

// ---------------------------------------------------------------------------
// Reduce ICH partials [ic][o][b] -> out [b][o], with 32x32 LDS transpose so
// both the ws reads and the out writes are coalesced.
// grid: (OUTPUT/32=4, BATCH/32=32), block: (32, 8)
// ---------------------------------------------------------------------------
__global__ void reduce_kernel(const float* __restrict__ partials,
                              float* __restrict__ out) {
    __shared__ float tile[32][33];
    const int o0 = blockIdx.x * 32;
    const int b0 = blockIdx.y * 32;
    const int tx = threadIdx.x;
    const int ty = threadIdx.y;
#pragma unroll
    for (int r = ty; r < 32; r += 8) {
        float v = 0.0f;
#pragma unroll
        for (int ic = 0; ic < ICH; ++ic)
            v += partials[((size_t)ic * OUTPUT_SIZE + o0 + r) * BATCH + b0 + tx];
        tile[r][tx] = v;
    }
    __syncthreads();
#pragma unroll
    for (int r = ty; r < 32; r += 8)
        out[(size_t)(b0 + r) * OUTPUT_SIZE + o0 + tx] = tile[tx][r];
}

extern "C" void kernel_launch(void* const* d_in, const int* in_sizes, int n_in,
                              void* d_out, int out_size, void* d_ws, size_t ws_size,
                              hipStream_t stream) {
    const float* x  = (const float*)d_in[0];
    const float* W1 = (const float*)d_in[1];
    const float* b1 = (const float*)d_in[2];
    const float* W2 = (const float*)d_in[3];
    const float* b2 = (const float*)d_in[4];
    const float* W3 = (const float*)d_in[5];
    const float* b3 = (const float*)d_in[6];
    float* out = (float*)d_out;

    const size_t xt_elems   = (size_t)INPUT_SIZE * BATCH;                 // 128K
    const size_t part_elems = (size_t)ICH * OUTPUT_SIZE * BATCH;          // 1M
    const size_t need_bytes = (xt_elems + part_elems) * sizeof(float);    // 4.5MB

    dim3 tgrid(INPUT_SIZE / 32, BATCH / 32);
    dim3 tblk(32, 8);
    dim3 mgrid(OUTPUT_SIZE, ICH);

    if (ws_size >= need_bytes) {
        float* xT       = (float*)d_ws;
        float* partials = xT + xt_elems;
        transpose_x_kernel<<<tgrid, tblk, 0, stream>>>(x, xT);
        mlpkan_kernel<true><<<mgrid, 256, 0, stream>>>(xT, W1, b1, W2, b2, W3, b3,
                                                       partials, out);
        dim3 rgrid(OUTPUT_SIZE / 32, BATCH / 32);
        reduce_kernel<<<rgrid, tblk, 0, stream>>>(partials, out);
    } else if (ws_size >= xt_elems * sizeof(float)) {
        float* xT = (float*)d_ws;
        transpose_x_kernel<<<tgrid, tblk, 0, stream>>>(x, xT);
        const int n = BATCH * OUTPUT_SIZE;
        zero_out_kernel<<<(n + 255) / 256, 256, 0, stream>>>(out, n);
        mlpkan_kernel<false><<<mgrid, 256, 0, stream>>>(xT, W1, b1, W2, b2, W3, b3,
                                                        nullptr, out);
    } else {
        // last resort: no ws at all (shouldn't happen) — uncoalesced x reads
        const int n = BATCH * OUTPUT_SIZE;
        zero_out_kernel<<<(n + 255) / 256, 256, 0, stream>>>(out, n);
        mlpkan_kernel<false><<<mgrid, 256, 0, stream>>>(x, W1, b1, W2, b2, W3, b3,
                                                        nullptr, out);
    }
}

// Round 4
// 111.788 us; speedup vs baseline: 2.6825x; 1.4344x over previous
//
#include <hip/hip_runtime.h>

#define INPUT_SIZE 128
#define OUTPUT_SIZE 128
#define HIDDEN 8
#define BATCH 1024

#define ICH 16                   // i-chunks (blockIdx.y)
#define IPC (INPUT_SIZE / ICH)   // 8 i's per chunk
#define TPB 128                  // threads per block (2 waves)
#define BPT 8                    // batch elements per thread -> 128*8 = 1024
#define WPI 100                  // floats per i in LDS: w1[8] b1[8] w2[64] b2[8] w3[8] b3 pad3

// ---------------------------------------------------------------------------
// Transpose x [B,I] -> xT [I,B]
// ---------------------------------------------------------------------------
__global__ void transpose_x_kernel(const float* __restrict__ x,
                                   float* __restrict__ xT) {
    __shared__ float tile[32][33];
    const int i0 = blockIdx.x * 32;
    const int b0 = blockIdx.y * 32;
    const int tx = threadIdx.x;
    const int ty = threadIdx.y;
#pragma unroll
    for (int r = ty; r < 32; r += 8)
        tile[r][tx] = x[(b0 + r) * INPUT_SIZE + (i0 + tx)];
    __syncthreads();
#pragma unroll
    for (int r = ty; r < 32; r += 8)
        xT[(i0 + r) * BATCH + (b0 + tx)] = tile[tx][r];
}

__global__ void zero_out_kernel(float* __restrict__ out, int n) {
    int idx = blockIdx.x * blockDim.x + threadIdx.x;
    if (idx < n) out[idx] = 0.0f;
}

// ---------------------------------------------------------------------------
// Main kernel. block = (o, ic). Stage this block's IPC*97 weights into LDS
// once (coalesced vector loads), then loop i: hoist weights LDS->VGPR
// (ds_read_b128 broadcasts), run BPT independent batch chains of pure FMA.
// ---------------------------------------------------------------------------
template <bool PARTIALS>
__global__ __launch_bounds__(TPB, 3)
void mlpkan_kernel(const float* __restrict__ xT,
                   const float* __restrict__ W1, const float* __restrict__ b1,
                   const float* __restrict__ W2, const float* __restrict__ b2,
                   const float* __restrict__ W3, const float* __restrict__ b3,
                   float* __restrict__ partials, float* __restrict__ out) {
    __shared__ float wlds[IPC][WPI];

    const int o   = blockIdx.x;
    const int ic  = blockIdx.y;
    const int tid = threadIdx.x;

    // ---- stage weights: W2 = 8 i's x 16 float4 = 128 threads x 1 float4 ----
    {
        const int ii  = tid >> 4;          // 0..7
        const int idx = tid & 15;          // 0..15
        const int n   = (ic * IPC + ii) * OUTPUT_SIZE + o;
        const float4 v = *(const float4*)(W2 + (size_t)n * 64 + idx * 4);
        *(float4*)&wlds[ii][16 + idx * 4] = v;

        if (tid < 64) {
            const int ii2 = tid >> 3;      // 0..7
            const int k   = tid & 7;       // 0..7
            const int n2  = (ic * IPC + ii2) * OUTPUT_SIZE + o;
            wlds[ii2][0  + k] = W1[(size_t)n2 * HIDDEN + k];
            wlds[ii2][8  + k] = b1[(size_t)n2 * HIDDEN + k];
            wlds[ii2][80 + k] = b2[(size_t)n2 * HIDDEN + k];
            wlds[ii2][88 + k] = W3[(size_t)n2 * HIDDEN + k];
            if (k == 0) wlds[ii2][96] = b3[n2];
        }
    }
    __syncthreads();

    float acc[BPT];
#pragma unroll
    for (int j = 0; j < BPT; ++j) acc[j] = 0.0f;

    for (int ii = 0; ii < IPC; ++ii) {
        const int i = ic * IPC + ii;

        // x values first (global loads overlap the ds_reads below)
        float s[BPT];
#pragma unroll
        for (int j = 0; j < BPT; ++j)
            s[j] = xT[(size_t)i * BATCH + tid + j * TPB];

        // ---- hoist weights LDS -> VGPR as float4 (ds_read_b128) ----
        const float* w = &wlds[ii][0];
        float w1r[8], b1r[8], w2r[64], b2r[8], w3r[8];
#pragma unroll
        for (int q = 0; q < 2; ++q) {
            float4 a = *(const float4*)(w + 0 + 4 * q);
            w1r[4*q] = a.x; w1r[4*q+1] = a.y; w1r[4*q+2] = a.z; w1r[4*q+3] = a.w;
            float4 bvec = *(const float4*)(w + 8 + 4 * q);
            b1r[4*q] = bvec.x; b1r[4*q+1] = bvec.y; b1r[4*q+2] = bvec.z; b1r[4*q+3] = bvec.w;
            float4 c = *(const float4*)(w + 80 + 4 * q);
            b2r[4*q] = c.x; b2r[4*q+1] = c.y; b2r[4*q+2] = c.z; b2r[4*q+3] = c.w;
            float4 d = *(const float4*)(w + 88 + 4 * q);
            w3r[4*q] = d.x; w3r[4*q+1] = d.y; w3r[4*q+2] = d.z; w3r[4*q+3] = d.w;
        }
#pragma unroll
        for (int q = 0; q < 16; ++q) {
            float4 t = *(const float4*)(w + 16 + 4 * q);
            w2r[4*q] = t.x; w2r[4*q+1] = t.y; w2r[4*q+2] = t.z; w2r[4*q+3] = t.w;
        }
        const float b3r = w[96];

        // ---- BPT independent fp32 FMA chains ----
#pragma unroll
        for (int j = 0; j < BPT; ++j) {
            const float s_ = s[j];
            float h1[HIDDEN];
#pragma unroll
            for (int k = 0; k < HIDDEN; ++k)
                h1[k] = fmaxf(fmaf(w1r[k], s_, b1r[k]), 0.0f);
            float h2[HIDDEN];
#pragma unroll
            for (int h = 0; h < HIDDEN; ++h) {
                float v = b2r[h];
#pragma unroll
                for (int k = 0; k < HIDDEN; ++k)
                    v = fmaf(w2r[h * HIDDEN + k], h1[k], v);
                h2[h] = fmaxf(v, 0.0f);
            }
            float v = b3r;
#pragma unroll
            for (int k = 0; k < HIDDEN; ++k)
                v = fmaf(w3r[k], h2[k], v);
            acc[j] += v;
        }
    }

    if (PARTIALS) {
#pragma unroll
        for (int j = 0; j < BPT; ++j)
            partials[((size_t)ic * OUTPUT_SIZE + o) * BATCH + tid + j * TPB] = acc[j];
    } else {
#pragma unroll
        for (int j = 0; j < BPT; ++j)
            atomicAdd(&out[(size_t)(tid + j * TPB) * OUTPUT_SIZE + o], acc[j]);
    }
}

// ---------------------------------------------------------------------------
// Reduce ICH partials [ic][o][b] -> out [b][o] with LDS transpose.
// grid: (OUTPUT/32, BATCH/32), block: (32, 8)
// ---------------------------------------------------------------------------
__global__ void reduce_kernel(const float* __restrict__ partials,
                              float* __restrict__ out) {
    __shared__ float tile[32][33];
    const int o0 = blockIdx.x * 32;
    const int b0 = blockIdx.y * 32;
    const int tx = threadIdx.x;
    const int ty = threadIdx.y;
#pragma unroll
    for (int r = ty; r < 32; r += 8) {
        float v = 0.0f;
#pragma unroll
        for (int ic = 0; ic < ICH; ++ic)
            v += partials[((size_t)ic * OUTPUT_SIZE + o0 + r) * BATCH + b0 + tx];
        tile[r][tx] = v;
    }
    __syncthreads();
#pragma unroll
    for (int r = ty; r < 32; r += 8)
        out[(size_t)(b0 + r) * OUTPUT_SIZE + o0 + tx] = tile[tx][r];
}

extern "C" void kernel_launch(void* const* d_in, const int* in_sizes, int n_in,
                              void* d_out, int out_size, void* d_ws, size_t ws_size,
                              hipStream_t stream) {
    const float* x  = (const float*)d_in[0];
    const float* W1 = (const float*)d_in[1];
    const float* b1 = (const float*)d_in[2];
    const float* W2 = (const float*)d_in[3];
    const float* b2 = (const float*)d_in[4];
    const float* W3 = (const float*)d_in[5];
    const float* b3 = (const float*)d_in[6];
    float* out = (float*)d_out;

    const size_t xt_elems   = (size_t)INPUT_SIZE * BATCH;              // 128K
    const size_t part_elems = (size_t)ICH * OUTPUT_SIZE * BATCH;       // 2M
    const size_t need_bytes = (xt_elems + part_elems) * sizeof(float); // 8.5MB

    dim3 tgrid(INPUT_SIZE / 32, BATCH / 32);
    dim3 tblk(32, 8);
    dim3 mgrid(OUTPUT_SIZE, ICH);

    if (ws_size >= need_bytes) {
        float* xT       = (float*)d_ws;
        float* partials = xT + xt_elems;
        transpose_x_kernel<<<tgrid, tblk, 0, stream>>>(x, xT);
        mlpkan_kernel<true><<<mgrid, TPB, 0, stream>>>(xT, W1, b1, W2, b2, W3, b3,
                                                       partials, out);
        dim3 rgrid(OUTPUT_SIZE / 32, BATCH / 32);
        reduce_kernel<<<rgrid, tblk, 0, stream>>>(partials, out);
    } else if (ws_size >= xt_elems * sizeof(float)) {
        float* xT = (float*)d_ws;
        transpose_x_kernel<<<tgrid, tblk, 0, stream>>>(x, xT);
        const int n = BATCH * OUTPUT_SIZE;
        zero_out_kernel<<<(n + 255) / 256, 256, 0, stream>>>(out, n);
        mlpkan_kernel<false><<<mgrid, TPB, 0, stream>>>(xT, W1, b1, W2, b2, W3, b3,
                                                        nullptr, out);
    } else {
        const int n = BATCH * OUTPUT_SIZE;
        zero_out_kernel<<<(n + 255) / 256, 256, 0, stream>>>(out, n);
        mlpkan_kernel<false><<<mgrid, TPB, 0, stream>>>(x, W1, b1, W2, b2, W3, b3,
                                                        nullptr, out);
    }
}

// Round 5
// 110.771 us; speedup vs baseline: 2.7071x; 1.0092x over previous
//
#include <hip/hip_runtime.h>

#define INPUT_SIZE 128
#define OUTPUT_SIZE 128
#define HIDDEN 8
#define BATCH 1024

#define ICH 16                   // i-chunks (blockIdx.y)
#define IPC (INPUT_SIZE / ICH)   // 8 i's per chunk
#define TPB 128                  // threads per block (2 waves)
#define BPT 8                    // batch elements per thread -> 128*8 = 1024
#define WPI 100                  // floats per i in LDS (25 float4 + b3 + pad)

// ---------------------------------------------------------------------------
// Transpose x [B,I] -> xT [I,B]
// ---------------------------------------------------------------------------
__global__ void transpose_x_kernel(const float* __restrict__ x,
                                   float* __restrict__ xT) {
    __shared__ float tile[32][33];
    const int i0 = blockIdx.x * 32;
    const int b0 = blockIdx.y * 32;
    const int tx = threadIdx.x;
    const int ty = threadIdx.y;
#pragma unroll
    for (int r = ty; r < 32; r += 8)
        tile[r][tx] = x[(b0 + r) * INPUT_SIZE + (i0 + tx)];
    __syncthreads();
#pragma unroll
    for (int r = ty; r < 32; r += 8)
        xT[(i0 + r) * BATCH + (b0 + tx)] = tile[tx][r];
}

__global__ void zero_out_kernel(float* __restrict__ out, int n) {
    int idx = blockIdx.x * blockDim.x + threadIdx.x;
    if (idx < n) out[idx] = 0.0f;
}

// ---------------------------------------------------------------------------
// Main kernel. block = (o, ic). Stage IPC*97 weights into LDS once, then per
// i: hoist ALL weights LDS->VGPR as 25 named float4 (ds_read_b128 broadcast),
// consumed DIRECTLY by the FMA chains (no unpack movs). launch_bounds(.,2)
// lifts the VGPR cap to ~256 so the hoist is not sunk back into the j-loop.
// ---------------------------------------------------------------------------
template <bool PARTIALS>
__global__ __launch_bounds__(TPB, 2)
void mlpkan_kernel(const float* __restrict__ xT,
                   const float* __restrict__ W1, const float* __restrict__ b1,
                   const float* __restrict__ W2, const float* __restrict__ b2,
                   const float* __restrict__ W3, const float* __restrict__ b3,
                   float* __restrict__ partials, float* __restrict__ out) {
    __shared__ float wlds[IPC][WPI];

    const int o   = blockIdx.x;
    const int ic  = blockIdx.y;
    const int tid = threadIdx.x;

    // ---- stage weights: W2 = 8 i's x 16 float4 = 128 threads x 1 float4 ----
    {
        const int ii  = tid >> 4;          // 0..7
        const int idx = tid & 15;          // 0..15
        const int n   = (ic * IPC + ii) * OUTPUT_SIZE + o;
        const float4 v = *(const float4*)(W2 + (size_t)n * 64 + idx * 4);
        *(float4*)&wlds[ii][16 + idx * 4] = v;

        if (tid < 64) {
            const int ii2 = tid >> 3;      // 0..7
            const int k   = tid & 7;       // 0..7
            const int n2  = (ic * IPC + ii2) * OUTPUT_SIZE + o;
            wlds[ii2][0  + k] = W1[(size_t)n2 * HIDDEN + k];
            wlds[ii2][8  + k] = b1[(size_t)n2 * HIDDEN + k];
            wlds[ii2][80 + k] = b2[(size_t)n2 * HIDDEN + k];
            wlds[ii2][88 + k] = W3[(size_t)n2 * HIDDEN + k];
            if (k == 0) wlds[ii2][96] = b3[n2];
        }
    }
    __syncthreads();

    float acc[BPT];
#pragma unroll
    for (int j = 0; j < BPT; ++j) acc[j] = 0.0f;

    for (int ii = 0; ii < IPC; ++ii) {
        const int i = ic * IPC + ii;

        // x values (coalesced; issue early, overlap the ds_reads)
        float s[BPT];
#pragma unroll
        for (int j = 0; j < BPT; ++j)
            s[j] = xT[(size_t)i * BATCH + tid + j * TPB];

        // ---- full weight hoist: 25 x ds_read_b128, used directly ----
        const float4* wq = (const float4*)(&wlds[ii][0]);
        const float4 w1a = wq[0],  w1b = wq[1];
        const float4 b1a = wq[2],  b1b = wq[3];
        float4 w2q[16];
#pragma unroll
        for (int q = 0; q < 16; ++q) w2q[q] = wq[4 + q];
        const float4 b2a = wq[20], b2b = wq[21];
        const float4 w3a = wq[22], w3b = wq[23];
        const float  b3r = wlds[ii][96];

        // SSA aliases (no VALU cost after SROA)
        const float w1r[8] = {w1a.x, w1a.y, w1a.z, w1a.w, w1b.x, w1b.y, w1b.z, w1b.w};
        const float b1r[8] = {b1a.x, b1a.y, b1a.z, b1a.w, b1b.x, b1b.y, b1b.z, b1b.w};
        const float b2r[8] = {b2a.x, b2a.y, b2a.z, b2a.w, b2b.x, b2b.y, b2b.z, b2b.w};
        const float w3r[8] = {w3a.x, w3a.y, w3a.z, w3a.w, w3b.x, w3b.y, w3b.z, w3b.w};

        // ---- BPT independent fp32 FMA chains ----
#pragma unroll
        for (int j = 0; j < BPT; ++j) {
            const float sj = s[j];
            float h1[8];
#pragma unroll
            for (int k = 0; k < 8; ++k)
                h1[k] = fmaxf(fmaf(w1r[k], sj, b1r[k]), 0.0f);
            float h2[8];
#pragma unroll
            for (int h = 0; h < 8; ++h) {
                const float4 qa = w2q[2 * h];
                const float4 qb = w2q[2 * h + 1];
                float v = b2r[h];
                v = fmaf(qa.x, h1[0], v); v = fmaf(qa.y, h1[1], v);
                v = fmaf(qa.z, h1[2], v); v = fmaf(qa.w, h1[3], v);
                v = fmaf(qb.x, h1[4], v); v = fmaf(qb.y, h1[5], v);
                v = fmaf(qb.z, h1[6], v); v = fmaf(qb.w, h1[7], v);
                h2[h] = fmaxf(v, 0.0f);
            }
            float v = b3r;
#pragma unroll
            for (int k = 0; k < 8; ++k)
                v = fmaf(w3r[k], h2[k], v);
            acc[j] += v;
        }
    }

    if (PARTIALS) {
#pragma unroll
        for (int j = 0; j < BPT; ++j)
            partials[((size_t)ic * OUTPUT_SIZE + o) * BATCH + tid + j * TPB] = acc[j];
    } else {
#pragma unroll
        for (int j = 0; j < BPT; ++j)
            atomicAdd(&out[(size_t)(tid + j * TPB) * OUTPUT_SIZE + o], acc[j]);
    }
}

// ---------------------------------------------------------------------------
// Reduce ICH partials [ic][o][b] -> out [b][o] with LDS transpose.
// grid: (OUTPUT/32, BATCH/32), block: (32, 8)
// ---------------------------------------------------------------------------
__global__ void reduce_kernel(const float* __restrict__ partials,
                              float* __restrict__ out) {
    __shared__ float tile[32][33];
    const int o0 = blockIdx.x * 32;
    const int b0 = blockIdx.y * 32;
    const int tx = threadIdx.x;
    const int ty = threadIdx.y;
#pragma unroll
    for (int r = ty; r < 32; r += 8) {
        float v = 0.0f;
#pragma unroll
        for (int ic = 0; ic < ICH; ++ic)
            v += partials[((size_t)ic * OUTPUT_SIZE + o0 + r) * BATCH + b0 + tx];
        tile[r][tx] = v;
    }
    __syncthreads();
#pragma unroll
    for (int r = ty; r < 32; r += 8)
        out[(size_t)(b0 + r) * OUTPUT_SIZE + o0 + tx] = tile[tx][r];
}

extern "C" void kernel_launch(void* const* d_in, const int* in_sizes, int n_in,
                              void* d_out, int out_size, void* d_ws, size_t ws_size,
                              hipStream_t stream) {
    const float* x  = (const float*)d_in[0];
    const float* W1 = (const float*)d_in[1];
    const float* b1 = (const float*)d_in[2];
    const float* W2 = (const float*)d_in[3];
    const float* b2 = (const float*)d_in[4];
    const float* W3 = (const float*)d_in[5];
    const float* b3 = (const float*)d_in[6];
    float* out = (float*)d_out;

    const size_t xt_elems   = (size_t)INPUT_SIZE * BATCH;              // 128K
    const size_t part_elems = (size_t)ICH * OUTPUT_SIZE * BATCH;       // 2M
    const size_t need_bytes = (xt_elems + part_elems) * sizeof(float); // 8.5MB

    dim3 tgrid(INPUT_SIZE / 32, BATCH / 32);
    dim3 tblk(32, 8);
    dim3 mgrid(OUTPUT_SIZE, ICH);

    if (ws_size >= need_bytes) {
        float* xT       = (float*)d_ws;
        float* partials = xT + xt_elems;
        transpose_x_kernel<<<tgrid, tblk, 0, stream>>>(x, xT);
        mlpkan_kernel<true><<<mgrid, TPB, 0, stream>>>(xT, W1, b1, W2, b2, W3, b3,
                                                       partials, out);
        dim3 rgrid(OUTPUT_SIZE / 32, BATCH / 32);
        reduce_kernel<<<rgrid, tblk, 0, stream>>>(partials, out);
    } else if (ws_size >= xt_elems * sizeof(float)) {
        float* xT = (float*)d_ws;
        transpose_x_kernel<<<tgrid, tblk, 0, stream>>>(x, xT);
        const int n = BATCH * OUTPUT_SIZE;
        zero_out_kernel<<<(n + 255) / 256, 256, 0, stream>>>(out, n);
        mlpkan_kernel<false><<<mgrid, TPB, 0, stream>>>(xT, W1, b1, W2, b2, W3, b3,
                                                        nullptr, out);
    } else {
        const int n = BATCH * OUTPUT_SIZE;
        zero_out_kernel<<<(n + 255) / 256, 256, 0, stream>>>(out, n);
        mlpkan_kernel<false><<<mgrid, TPB, 0, stream>>>(x, W1, b1, W2, b2, W3, b3,
                                                        nullptr, out);
    }
}